// Round 6
// baseline (725.921 us; speedup 1.0000x reference)
//
#include <hip/hip_runtime.h>

typedef short bf16x8 __attribute__((ext_vector_type(8)));
typedef float f32x4 __attribute__((ext_vector_type(4)));
typedef unsigned short u16;

#define NNODE 196608
#define FF 32
#define COLS 256   // UP * OUT_FEATURES
#define KTOT 288   // KK * FF
#define WELEMS (COLS * KTOT)   // 73728 elems = 144 KB bf16
#define TPB 6                  // tiles per block (1536 / 256)

__device__ __forceinline__ u16 f2bf(float f) {
    unsigned u = __builtin_bit_cast(unsigned, f);
    return (u16)((u + 0x7fffu + ((u >> 16) & 1u)) >> 16);  // RTNE
}

// prep 1: x f32 -> bf16, 8 elems/thread
__global__ void cvt_x(const float* __restrict__ x, u16* __restrict__ xb, int n8) {
    int i = blockIdx.x * blockDim.x + threadIdx.x;
    if (i >= n8) return;
    f32x4 v0 = *((const f32x4*)x + (size_t)i * 2);
    f32x4 v1 = *((const f32x4*)x + (size_t)i * 2 + 1);
    union { u16 h[8]; bf16x8 v; } r;
    #pragma unroll
    for (int j = 0; j < 4; ++j) r.h[j] = f2bf(v0[j]);
    #pragma unroll
    for (int j = 0; j < 4; ++j) r.h[4 + j] = f2bf(v1[j]);
    *((bf16x8*)xb + i) = r.v;
}

// prep 2: W (K,F,UP,O) f32 -> Wt bf16, MFMA fragment-linear:
// Wt[f*512 + lane*8 + e] = W[kf][c], f = kk*16+ct, c = ct*16+(lane&15),
// kf = kk*32 + (lane>>4)*8 + e. Wave ds_read_b128 of a frag: lane-linear.
__global__ void cvt_w(const float* __restrict__ W, u16* __restrict__ Wt) {
    int gid = blockIdx.x * 256 + threadIdx.x;   // 73728 total
    int f      = gid >> 9;
    int within = gid & 511;
    int lane   = within >> 3;
    int e      = within & 7;
    int kk = f >> 4, ct = f & 15;
    int cl = lane & 15, q = lane >> 4;
    int c  = ct * 16 + cl;
    int kf = kk * 32 + q * 8 + e;
    Wt[gid] = f2bf(W[(size_t)kf * COLS + c]);
}

// main: grid 256 (1 block/CU by LDS), 512 thr = 8 waves, static 6 tiles/blk.
// Tile = 128 nodes x 2 t-slices x 256 cols; wave = 16 nodes x 2 t (C=1).
// OPERAND-SWAPPED MFMA: A = W-frag (LDS), B = x-frag (gather). D row = col
// index -> lane owns out[node][ct*16+q*4 .. +3] -> f32x4 stores, imm offsets.
// FIFO discipline: next tile's adjc row @kk=5, its first gather @kk=8, THEN
// this tile's 32 stores -> gather consume-waits never drain the store backlog.
// No barriers / atomics after prologue.
__global__ __launch_bounds__(512, 2) void updown_main(
    const u16* __restrict__ xb, const u16* __restrict__ Wt,
    const int* __restrict__ adjc, const float* __restrict__ bias,
    float* __restrict__ out)
{
    __shared__ __align__(16) u16 wlds[WELEMS];   // 144 KB, read-only after load
    __shared__ __align__(16) float blds[COLS];   // 1 KB bias

    const int tid = threadIdx.x;

    #pragma unroll
    for (int i = 0; i < 18; ++i)
        *(bf16x8*)(wlds + i * 4096 + tid * 8) =
            *(const bf16x8*)(Wt + i * 4096 + tid * 8);
    if (tid < 64) ((f32x4*)blds)[tid] = ((const f32x4*)bias)[tid];
    __syncthreads();   // the only barrier

    const int w    = tid >> 6;
    const int lane = tid & 63;
    const int l15  = lane & 15;
    const int q    = lane >> 4;
    const u16* xb1   = xb + (size_t)NNODE * FF;       // t=1 slice
    const u16* wbase = wlds + lane * 8;               // + kk*8192 + ct*512
    const float* bb  = blds + q * 4;                  // + ct*16

    int node = blockIdx.x * (TPB * 128) + w * 16 + l15;

    int arowC[9];
    #pragma unroll
    for (int k = 0; k < 9; ++k) arowC[k] = adjc[(size_t)node * 9 + k];
    bf16x8 aC0 = *(const bf16x8*)(xb  + (size_t)arowC[0] * FF + q * 8);
    bf16x8 aC1 = *(const bf16x8*)(xb1 + (size_t)arowC[0] * FF + q * 8);
    int idxN = arowC[1];

    for (int tt = 0; tt < TPB; ++tt) {
        const bool last = (tt == TPB - 1);
        const int nodeN = node + 128;

        // acc init = bias (folds the epilogue add; lgkm counter, not vmcnt)
        f32x4 acc0[16], acc1[16];
        #pragma unroll
        for (int ct = 0; ct < 16; ++ct) {
            f32x4 bq = *(const f32x4*)(bb + ct * 16);
            acc0[ct] = bq;
            acc1[ct] = bq;
        }

        int arowN[9];
        bf16x8 g00, g01;
        #pragma unroll
        for (int kk = 0; kk < 9; ++kk) {
            bf16x8 aN0, aN1;
            if (kk < 8) {
                aN0 = *(const bf16x8*)(xb  + (size_t)idxN * FF + q * 8);
                aN1 = *(const bf16x8*)(xb1 + (size_t)idxN * FF + q * 8);
            }
            if (kk == 5 && !last) {
                #pragma unroll
                for (int k2 = 0; k2 < 9; ++k2)
                    arowN[k2] = adjc[(size_t)nodeN * 9 + k2];
            }
            if (kk == 8 && !last) {
                g00 = *(const bf16x8*)(xb  + (size_t)arowN[0] * FF + q * 8);
                g01 = *(const bf16x8*)(xb1 + (size_t)arowN[0] * FF + q * 8);
            }

            const u16* wk = wbase + kk * 8192;
            #pragma unroll
            for (int ct = 0; ct < 16; ++ct) {
                bf16x8 af = *(const bf16x8*)(wk + ct * 512);
                acc0[ct] = __builtin_amdgcn_mfma_f32_16x16x32_bf16(af, aC0, acc0[ct], 0, 0, 0);
                acc1[ct] = __builtin_amdgcn_mfma_f32_16x16x32_bf16(af, aC1, acc1[ct], 0, 0, 0);
            }
            if (kk < 8) {
                aC0 = aN0; aC1 = aN1;
                idxN = (kk < 7) ? arowC[kk + 2] : 0;
            }
        }

        // stores (issued AFTER next tile's first gathers -> stay in flight)
        float* o0 = out + (size_t)node * COLS + q * 4;
        float* o1 = out + ((size_t)NNODE + node) * COLS + q * 4;
        #pragma unroll
        for (int ct = 0; ct < 16; ++ct) {
            *(f32x4*)(o0 + ct * 16) = acc0[ct];
            *(f32x4*)(o1 + ct * 16) = acc1[ct];
        }

        if (!last) {
            #pragma unroll
            for (int k2 = 0; k2 < 9; ++k2) arowC[k2] = arowN[k2];
            aC0 = g00; aC1 = g01;
            idxN = arowC[1];
            node = nodeN;
        }
    }
}

extern "C" void kernel_launch(void* const* d_in, const int* in_sizes, int n_in,
                              void* d_out, int out_size, void* d_ws, size_t ws_size,
                              hipStream_t stream) {
    const float* x    = (const float*)d_in[0];
    const int*   adjc = (const int*)d_in[1];
    const float* W    = (const float*)d_in[2];
    const float* b    = (const float*)d_in[3];
    float* out = (float*)d_out;

    u16* xb = (u16*)d_ws;                            // 2*196608*32 bf16 = 25.2 MB
    u16* Wt = xb + (size_t)2 * NNODE * FF;           // 73728 bf16 = 144 KB

    cvt_x<<<dim3(6144), dim3(256), 0, stream>>>(x, xb, 1572864);
    cvt_w<<<dim3(288), dim3(256), 0, stream>>>(W, Wt);
    updown_main<<<dim3(256), dim3(512), 0, stream>>>(xb, Wt, adjc, b, out);
}

// Round 7
// 692.367 us; speedup vs baseline: 1.0485x; 1.0485x over previous
//
#include <hip/hip_runtime.h>

typedef short bf16x8 __attribute__((ext_vector_type(8)));
typedef float f32x4 __attribute__((ext_vector_type(4)));
typedef unsigned short u16;

#define NNODE 196608
#define FF 32
#define COLS 256   // UP * OUT_FEATURES
#define KTOT 288   // KK * FF
#define WELEMS (COLS * KTOT)   // 73728 elems = 144 KB bf16
#define TPB 6                  // tiles per block (1536 / 256)

__device__ __forceinline__ u16 f2bf(float f) {
    unsigned u = __builtin_bit_cast(unsigned, f);
    return (u16)((u + 0x7fffu + ((u >> 16) & 1u)) >> 16);  // RTNE
}

// prep 1: x (2,N,32) f32 -> xb2 bf16 INTERLEAVED: xb2[node][0:32]=t0 feats,
// xb2[node][32:64]=t1 feats -> one 128-B line per node (gather = 1 line).
__global__ void cvt_x(const float* __restrict__ x, u16* __restrict__ xb2, int n8) {
    int i = blockIdx.x * blockDim.x + threadIdx.x;
    if (i >= n8) return;
    int og   = i * 8;           // output element index (u16 units)
    int node = og >> 6;
    int rem  = og & 63;
    int s    = rem >> 5;        // t-slice
    int f0   = rem & 31;        // feature start (0,8,16,24)
    const float* src = x + ((size_t)s * NNODE + node) * FF + f0;
    f32x4 v0 = *(const f32x4*)src;
    f32x4 v1 = *(const f32x4*)(src + 4);
    union { u16 h[8]; bf16x8 v; } r;
    #pragma unroll
    for (int j = 0; j < 4; ++j) r.h[j] = f2bf(v0[j]);
    #pragma unroll
    for (int j = 0; j < 4; ++j) r.h[4 + j] = f2bf(v1[j]);
    *((bf16x8*)xb2 + i) = r.v;
}

// prep 2: W (K,F,UP,O) f32 -> Wt bf16, MFMA fragment-linear:
// Wt[f*512 + lane*8 + e] = W[kf][c], f = kk*16+ct, c = ct*16+(lane&15),
// kf = kk*32 + (lane>>4)*8 + e. Wave ds_read_b128 of a frag: lane-linear.
__global__ void cvt_w(const float* __restrict__ W, u16* __restrict__ Wt) {
    int gid = blockIdx.x * 256 + threadIdx.x;   // 73728 total
    int f      = gid >> 9;
    int within = gid & 511;
    int lane   = within >> 3;
    int e      = within & 7;
    int kk = f >> 4, ct = f & 15;
    int cl = lane & 15, q = lane >> 4;
    int c  = ct * 16 + cl;
    int kf = kk * 32 + q * 8 + e;
    Wt[gid] = f2bf(W[(size_t)kf * COLS + c]);
}

// main: grid 256 (1 blk/CU), 512 thr = 8 waves, static 6 tiles/blk, no
// barriers/atomics after prologue. Wave = 16 nodes x 2 t-slices (C=1).
// Operand-swapped MFMA (A = W-frag from LDS, B = x-frag gathered):
// lane owns out[node][ct*16+q*4..+3] -> f32x4 stores.
// Pipeline: gathers depth-2 (aC/aN/aNN); next tile's first 2 gathers issued
// BEFORE this tile's stores so the store backlog drains under compute.
__global__ __launch_bounds__(512, 2) void updown_main(
    const u16* __restrict__ xb2, const u16* __restrict__ Wt,
    const int* __restrict__ adjc, const float* __restrict__ bias,
    float* __restrict__ out)
{
    __shared__ __align__(16) u16 wlds[WELEMS];   // 144 KB, read-only after load
    __shared__ __align__(16) float blds[COLS];   // 1 KB bias

    const int tid = threadIdx.x;

    #pragma unroll
    for (int i = 0; i < 18; ++i)
        *(bf16x8*)(wlds + i * 4096 + tid * 8) =
            *(const bf16x8*)(Wt + i * 4096 + tid * 8);
    if (tid < 64) ((f32x4*)blds)[tid] = ((const f32x4*)bias)[tid];
    __syncthreads();   // the only barrier

    const int w    = tid >> 6;
    const int lane = tid & 63;
    const int l15  = lane & 15;
    const int q    = lane >> 4;
    const u16* wbase = wlds + lane * 8;   // + kk*8192 + ct*512
    const float* bb  = blds + q * 4;      // + ct*16

    int node = blockIdx.x * (TPB * 128) + w * 16 + l15;

    // tile-0 pipeline prologue: 2 gathers (2 lines) in flight
    int i0 = adjc[(size_t)node * 9 + 0];
    int i1 = adjc[(size_t)node * 9 + 1];
    const u16* g0 = xb2 + (size_t)i0 * 64 + q * 8;
    bf16x8 aC0 = *(const bf16x8*)g0;
    bf16x8 aC1 = *(const bf16x8*)(g0 + 32);
    const u16* g1 = xb2 + (size_t)i1 * 64 + q * 8;
    bf16x8 aN0 = *(const bf16x8*)g1;
    bf16x8 aN1 = *(const bf16x8*)(g1 + 32);

    for (int tt = 0; tt < TPB; ++tt) {
        const bool last = (tt == TPB - 1);

        // acc init = bias (lgkm counter — doesn't touch the vmcnt FIFO)
        f32x4 acc0[16], acc1[16];
        #pragma unroll
        for (int ct = 0; ct < 16; ++ct) {
            f32x4 bq = *(const f32x4*)(bb + ct * 16);
            acc0[ct] = bq;
            acc1[ct] = bq;
        }

        #pragma unroll
        for (int kk = 0; kk < 9; ++kk) {
            bf16x8 aNN0, aNN1;
            if (kk < 7) {   // keep gathers 2 steps ahead
                int inn = adjc[(size_t)node * 9 + kk + 2];
                const u16* g2 = xb2 + (size_t)inn * 64 + q * 8;
                aNN0 = *(const bf16x8*)g2;
                aNN1 = *(const bf16x8*)(g2 + 32);
            }
            const u16* wk = wbase + kk * 8192;
            #pragma unroll
            for (int ct = 0; ct < 16; ++ct) {
                bf16x8 af = *(const bf16x8*)(wk + ct * 512);
                acc0[ct] = __builtin_amdgcn_mfma_f32_16x16x32_bf16(af, aC0, acc0[ct], 0, 0, 0);
                acc1[ct] = __builtin_amdgcn_mfma_f32_16x16x32_bf16(af, aC1, acc1[ct], 0, 0, 0);
            }
            if (kk < 8) { aC0 = aN0; aC1 = aN1; }
            if (kk < 7) { aN0 = aNN0; aN1 = aNN1; }
        }

        // hand off: next tile's first 2 gathers BEFORE this tile's stores,
        // so the kk=0 consume-wait never drains the store backlog.
        const int nodeN = node + 128;
        bf16x8 nC0, nC1, nN0, nN1;
        if (!last) {
            int j0 = adjc[(size_t)nodeN * 9 + 0];
            int j1 = adjc[(size_t)nodeN * 9 + 1];
            const u16* h0 = xb2 + (size_t)j0 * 64 + q * 8;
            nC0 = *(const bf16x8*)h0;
            nC1 = *(const bf16x8*)(h0 + 32);
            const u16* h1 = xb2 + (size_t)j1 * 64 + q * 8;
            nN0 = *(const bf16x8*)h1;
            nN1 = *(const bf16x8*)(h1 + 32);
        }

        float* o0 = out + (size_t)node * COLS + q * 4;
        float* o1 = out + ((size_t)NNODE + node) * COLS + q * 4;
        #pragma unroll
        for (int ct = 0; ct < 16; ++ct) {
            *(f32x4*)(o0 + ct * 16) = acc0[ct];
            *(f32x4*)(o1 + ct * 16) = acc1[ct];
        }

        if (!last) {
            aC0 = nC0; aC1 = nC1;
            aN0 = nN0; aN1 = nN1;
            node = nodeN;
        }
    }
}

extern "C" void kernel_launch(void* const* d_in, const int* in_sizes, int n_in,
                              void* d_out, int out_size, void* d_ws, size_t ws_size,
                              hipStream_t stream) {
    const float* x    = (const float*)d_in[0];
    const int*   adjc = (const int*)d_in[1];
    const float* W    = (const float*)d_in[2];
    const float* b    = (const float*)d_in[3];
    float* out = (float*)d_out;

    u16* xb2 = (u16*)d_ws;                           // 196608*64 bf16 = 25.2 MB
    u16* Wt  = xb2 + (size_t)NNODE * 64;             // 73728 bf16 = 144 KB

    cvt_x<<<dim3(6144), dim3(256), 0, stream>>>(x, xb2, 1572864);
    cvt_w<<<dim3(288), dim3(256), 0, stream>>>(W, Wt);
    updown_main<<<dim3(256), dim3(512), 0, stream>>>(xb2, Wt, adjc, b, out);
}

// Round 8
// 143.920 us; speedup vs baseline: 5.0439x; 4.8108x over previous
//
#include <hip/hip_runtime.h>

typedef short bf16x8 __attribute__((ext_vector_type(8)));
typedef float f32x4 __attribute__((ext_vector_type(4)));
typedef unsigned short u16;

#define NNODE 196608
#define FF 32
#define COLS 256   // UP * OUT_FEATURES
#define KTOT 288   // KK * FF
#define WELEMS (COLS * KTOT)   // 73728 elems = 144 KB bf16
#define TPB 6                  // tiles per block (1536 / 256)

__device__ __forceinline__ u16 f2bf(float f) {
    unsigned u = __builtin_bit_cast(unsigned, f);
    return (u16)((u + 0x7fffu + ((u >> 16) & 1u)) >> 16);  // RTNE
}

// prep 1: x (2,N,32) f32 -> xb2 bf16 INTERLEAVED: xb2[node][0:32]=t0 feats,
// xb2[node][32:64]=t1 feats -> one 128-B line per node (gather = 1 line).
__global__ void cvt_x(const float* __restrict__ x, u16* __restrict__ xb2, int n8) {
    int i = blockIdx.x * blockDim.x + threadIdx.x;
    if (i >= n8) return;
    int og   = i * 8;           // output element index (u16 units)
    int node = og >> 6;
    int rem  = og & 63;
    int s    = rem >> 5;        // t-slice
    int f0   = rem & 31;        // feature start (0,8,16,24)
    const float* src = x + ((size_t)s * NNODE + node) * FF + f0;
    f32x4 v0 = *(const f32x4*)src;
    f32x4 v1 = *(const f32x4*)(src + 4);
    union { u16 h[8]; bf16x8 v; } r;
    #pragma unroll
    for (int j = 0; j < 4; ++j) r.h[j] = f2bf(v0[j]);
    #pragma unroll
    for (int j = 0; j < 4; ++j) r.h[4 + j] = f2bf(v1[j]);
    *((bf16x8*)xb2 + i) = r.v;
}

// prep 2: W (K,F,UP,O) f32 -> Wt bf16, MFMA fragment-linear:
// Wt[f*512 + lane*8 + e] = W[kf][c], f = kk*16+ct, c = ct*16+(lane&15),
// kf = kk*32 + (lane>>4)*8 + e. Wave ds_read_b128 of a frag: lane-linear.
__global__ void cvt_w(const float* __restrict__ W, u16* __restrict__ Wt) {
    int gid = blockIdx.x * 256 + threadIdx.x;   // 73728 total
    int f      = gid >> 9;
    int within = gid & 511;
    int lane   = within >> 3;
    int e      = within & 7;
    int kk = f >> 4, ct = f & 15;
    int cl = lane & 15, q = lane >> 4;
    int c  = ct * 16 + cl;
    int kf = kk * 32 + q * 8 + e;
    Wt[gid] = f2bf(W[(size_t)kf * COLS + c]);
}

// main: grid 256 (1 blk/CU via 145 KB LDS), 512 thr = 8 waves, static 6
// tiles/blk. Wave = 16 nodes x 2 t-slices (gather redundancy C=1).
// Operand-swapped MFMA (A = W-frag from LDS, B = x-frag gathered): lane
// owns out[node][ct*16+q*4..+3] -> 32 f32x4 stores/wave/tile.
// CRITICAL (R6/R7 lesson): NO live state crosses the tile seam except tt —
// carrying idx/gather regs across the seam while 128 acc regs are live
// caused ~430 MB/way scratch spill. Idx->gather chain broken by loading
// idx one full kk-iteration before its dependent gather.
__global__ __launch_bounds__(512, 2) void updown_main(
    const u16* __restrict__ xb2, const u16* __restrict__ Wt,
    const int* __restrict__ adjc, const float* __restrict__ bias,
    float* __restrict__ out)
{
    __shared__ __align__(16) u16 wlds[WELEMS];   // 144 KB, read-only after load
    __shared__ __align__(16) float blds[COLS];   // 1 KB bias

    const int tid = threadIdx.x;

    #pragma unroll
    for (int i = 0; i < 18; ++i)
        *(bf16x8*)(wlds + i * 4096 + tid * 8) =
            *(const bf16x8*)(Wt + i * 4096 + tid * 8);
    if (tid < 64) ((f32x4*)blds)[tid] = ((const f32x4*)bias)[tid];
    __syncthreads();   // the only full barrier

    const int w    = tid >> 6;
    const int lane = tid & 63;
    const int l15  = lane & 15;
    const int q    = lane >> 4;
    const u16* wbase = wlds + lane * 8;   // + kk*8192 + ct*512
    const float* bb  = blds + q * 4;      // + ct*16

    const int node0 = blockIdx.x * (TPB * 128) + w * 16 + l15;

    for (int tt = 0; tt < TPB; ++tt) {
        const int node  = node0 + tt * 128;
        const int* arow = adjc + (size_t)node * 9;

        // tile prologue: 2 gathers in flight + idx for the third
        int i0 = arow[0];
        int i1 = arow[1];
        const u16* g0 = xb2 + (size_t)i0 * 64 + q * 8;
        bf16x8 aC0 = *(const bf16x8*)g0;
        bf16x8 aC1 = *(const bf16x8*)(g0 + 32);
        const u16* g1 = xb2 + (size_t)i1 * 64 + q * 8;
        bf16x8 aN0 = *(const bf16x8*)g1;
        bf16x8 aN1 = *(const bf16x8*)(g1 + 32);
        int idxP = arow[2];   // idx one iteration ahead of its gather

        // acc init = bias (lgkm counter — doesn't touch the vmcnt FIFO)
        f32x4 acc0[16], acc1[16];
        #pragma unroll
        for (int ct = 0; ct < 16; ++ct) {
            f32x4 bq = *(const f32x4*)(bb + ct * 16);
            acc0[ct] = bq;
            acc1[ct] = bq;
        }

        #pragma unroll
        for (int kk = 0; kk < 9; ++kk) {
            bf16x8 aNN0, aNN1;
            if (kk < 7) {   // gather kk+2 using idx loaded last iteration
                const u16* g2 = xb2 + (size_t)idxP * 64 + q * 8;
                aNN0 = *(const bf16x8*)g2;
                aNN1 = *(const bf16x8*)(g2 + 32);
            }
            if (kk < 6) idxP = arow[kk + 3];   // idx for next iteration's gather

            const u16* wk = wbase + kk * 8192;
            #pragma unroll
            for (int ct = 0; ct < 16; ++ct) {
                bf16x8 af = *(const bf16x8*)(wk + ct * 512);
                acc0[ct] = __builtin_amdgcn_mfma_f32_16x16x32_bf16(af, aC0, acc0[ct], 0, 0, 0);
                acc1[ct] = __builtin_amdgcn_mfma_f32_16x16x32_bf16(af, aC1, acc1[ct], 0, 0, 0);
            }
            if (kk < 8) { aC0 = aN0; aC1 = aN1; }
            if (kk < 7) { aN0 = aNN0; aN1 = aNN1; }
        }

        // stores: lane-contiguous f32x4, dense full-line coverage
        float* o0 = out + (size_t)node * COLS + q * 4;
        float* o1 = o0 + (size_t)NNODE * COLS;
        #pragma unroll
        for (int ct = 0; ct < 16; ++ct) {
            *(f32x4*)(o0 + ct * 16) = acc0[ct];
            *(f32x4*)(o1 + ct * 16) = acc1[ct];
        }

        // phase-lock the 8 waves (L2 locality); raw barrier: NO vmcnt drain
        __builtin_amdgcn_s_barrier();
    }
}

extern "C" void kernel_launch(void* const* d_in, const int* in_sizes, int n_in,
                              void* d_out, int out_size, void* d_ws, size_t ws_size,
                              hipStream_t stream) {
    const float* x    = (const float*)d_in[0];
    const int*   adjc = (const int*)d_in[1];
    const float* W    = (const float*)d_in[2];
    const float* b    = (const float*)d_in[3];
    float* out = (float*)d_out;

    u16* xb2 = (u16*)d_ws;                           // 196608*64 bf16 = 25.2 MB
    u16* Wt  = xb2 + (size_t)NNODE * 64;             // 73728 bf16 = 144 KB

    cvt_x<<<dim3(6144), dim3(256), 0, stream>>>(x, xb2, 1572864);
    cvt_w<<<dim3(288), dim3(256), 0, stream>>>(W, Wt);
    updown_main<<<dim3(256), dim3(512), 0, stream>>>(xb2, Wt, adjc, b, out);
}